// Round 14
// baseline (175.752 us; speedup 1.0000x reference)
//
#include <hip/hip_runtime.h>
#include <math.h>

typedef float f4 __attribute__((ext_vector_type(4)));
typedef float f32x4 __attribute__((ext_vector_type(4)));
typedef __bf16 bf16x8 __attribute__((ext_vector_type(8)));
typedef unsigned short u16;
typedef u16 us8 __attribute__((ext_vector_type(8)));

#define BN_EPS 1e-3f

__device__ __forceinline__ u16 f2bf(float f) {
  unsigned u = __builtin_bit_cast(unsigned, f);
  unsigned r = u + 0x7fffu + ((u >> 16) & 1u);
  return (u16)(r >> 16);
}
__device__ __forceinline__ float bf2f(u16 h) {
  unsigned u = ((unsigned)h) << 16;
  return __builtin_bit_cast(float, u);
}

// One merged prep kernel, block-range sections (all 256-thread blocks):
//  S0 [0,4096):    x -> Xb = bf16(xb), Xsq = bf16(xb^2)   (BN inline)
//  S1 [4096,4608): Pth[j][k] bf16 (coefs^2 | -2*coefs^2*centers), cvec fp32
//  S2 [4608,4864): W1th[n][k] = bf16(W1[k][n]/scale_k)    (rescaled transpose)
//  S3 [4864,5376): Wth[n][k]  = bf16(W_out[k][n])
//  S4 [5376,5384): b1a[j] = b1[j] - sum_k shift_k*W1[k][j]/scale_k (GEMV)
__global__ __launch_bounds__(256) void prep_all_kernel(
    const float* __restrict__ x, const float* __restrict__ W1,
    const float* __restrict__ b1, const float* __restrict__ centers,
    const float* __restrict__ coefs, const float* __restrict__ gamma,
    const float* __restrict__ beta, const float* __restrict__ mean,
    const float* __restrict__ var, const float* __restrict__ W_out,
    u16* __restrict__ Xb, u16* __restrict__ Xsq, u16* __restrict__ Pth,
    float* __restrict__ cvec, u16* __restrict__ W1th, u16* __restrict__ Wth,
    float* __restrict__ b1a) {
  __shared__ float tsh[32][33];
  __shared__ float red[4][64];
  const int bid = blockIdx.x;
  const int tid = threadIdx.x;

  if (bid < 4096) {
    int gid = bid * 256 + tid;
    int m = gid >> 6;
    int d0 = (gid & 63) * 8;
    f4 v0 = *(const f4*)(x + (size_t)m * 512 + d0);
    f4 v1 = *(const f4*)(x + (size_t)m * 512 + d0 + 4);
    f4 g0 = *(const f4*)(gamma + d0);
    f4 g1 = *(const f4*)(gamma + d0 + 4);
    f4 be0 = *(const f4*)(beta + d0);
    f4 be1 = *(const f4*)(beta + d0 + 4);
    f4 mn0 = *(const f4*)(mean + d0);
    f4 mn1 = *(const f4*)(mean + d0 + 4);
    f4 va0 = *(const f4*)(var + d0);
    f4 va1 = *(const f4*)(var + d0 + 4);
    us8 ob, oq;
#pragma unroll
    for (int e = 0; e < 8; ++e) {
      float xv = (e < 4) ? v0[e] : v1[e - 4];
      float gv = (e < 4) ? g0[e] : g1[e - 4];
      float bv = (e < 4) ? be0[e] : be1[e - 4];
      float mv = (e < 4) ? mn0[e] : mn1[e - 4];
      float vv = (e < 4) ? va0[e] : va1[e - 4];
      float s = rsqrtf(vv + BN_EPS) * gv;
      float sh = bv - mv * s;
      float xbf = fmaf(xv, s, sh);
      ob[e] = f2bf(xbf);
      oq[e] = f2bf(xbf * xbf);
    }
    *(us8*)(Xb + (size_t)m * 512 + d0) = ob;
    *(us8*)(Xsq + (size_t)m * 512 + d0) = oq;
  } else if (bid < 4608) {
    int j = bid - 4096;
    int d = tid * 2;
    float acc = 0.f;
    u16 pa2[2], pb2[2];
#pragma unroll
    for (int e = 0; e < 2; ++e) {
      float cf = coefs[(size_t)j * 512 + d + e];
      float ce = centers[(size_t)j * 512 + d + e];
      float a = cf * cf;
      pa2[e] = f2bf(a);
      pb2[e] = f2bf(-2.f * a * ce);
      acc = fmaf(a * ce, ce, acc);
    }
    *(unsigned*)(Pth + (size_t)j * 1024 + d) =
        ((unsigned)pa2[1] << 16) | pa2[0];
    *(unsigned*)(Pth + (size_t)j * 1024 + 512 + d) =
        ((unsigned)pb2[1] << 16) | pb2[0];
#pragma unroll
    for (int off = 32; off; off >>= 1) acc += __shfl_xor(acc, off);
    if ((tid & 63) == 0) red[0][tid >> 6] = acc;
    __syncthreads();
    if (tid == 0)
      cvec[j] = red[0][0] + red[0][1] + red[0][2] + red[0][3];
  } else if (bid < 4864) {
    int i = bid - 4608;
    int lx = tid & 31, ly = tid >> 5;
    int n0 = (i & 15) * 32, k0 = (i >> 4) * 32;
#pragma unroll
    for (int q = 0; q < 4; ++q)
      tsh[ly + 8 * q][lx] = W1[(size_t)(k0 + ly + 8 * q) * 512 + n0 + lx];
    __syncthreads();
    int k = k0 + lx;
    float s = rsqrtf(var[k] + BN_EPS) * gamma[k];
#pragma unroll
    for (int q = 0; q < 4; ++q) {
      float v = tsh[lx][ly + 8 * q] / s;
      W1th[(size_t)(n0 + ly + 8 * q) * 512 + k] = f2bf(v);
    }
  } else if (bid < 5376) {
    int i = bid - 4864;
    int lx = tid & 31, ly = tid >> 5;
    int n0 = (i & 15) * 32, k0 = (i >> 4) * 32;
#pragma unroll
    for (int q = 0; q < 4; ++q)
      tsh[ly + 8 * q][lx] = W_out[(size_t)(k0 + ly + 8 * q) * 512 + n0 + lx];
    __syncthreads();
#pragma unroll
    for (int q = 0; q < 4; ++q) {
      float v = tsh[lx][ly + 8 * q];
      Wth[(size_t)(n0 + ly + 8 * q) * 1024 + k0 + lx] = f2bf(v);
    }
  } else {
    int b = bid - 5376;
    int lane = tid & 63;
    int kq = tid >> 6;
    int j = b * 64 + lane;
    float partial = 0.f;
    for (int i = 0; i < 128; ++i) {
      int k = kq * 128 + i;
      float s = rsqrtf(var[k] + BN_EPS) * gamma[k];
      float sh = beta[k] - mean[k] * s;
      partial = fmaf(sh, W1[(size_t)k * 512 + j] / s, partial);
    }
    red[kq][lane] = partial;
    __syncthreads();
    if (tid < 64) {
      float t = red[0][tid] + red[1][tid] + red[2][tid] + red[3][tid];
      b1a[b * 64 + tid] = b1[b * 64 + tid] - t;
    }
  }
}

__device__ __forceinline__ void wait_vm8() {
  asm volatile("s_waitcnt vmcnt(8)" ::: "memory");
}
__device__ __forceinline__ void wait_vm9() {
  asm volatile("s_waitcnt vmcnt(9)" ::: "memory");
}
__device__ __forceinline__ void wait_vm0() {
  asm volatile("s_waitcnt vmcnt(0)" ::: "memory");
}
__device__ __forceinline__ void sbar() { __builtin_amdgcn_s_barrier(); }
__device__ __forceinline__ void sgb0() { __builtin_amdgcn_sched_barrier(0); }

// Merged G1+G2, counted-vmcnt 2-tile-ahead pipeline. 1024 blocks, 128x128,
// BK=64, LDS 64KB. (unchanged from round 11)
__global__ __launch_bounds__(256, 2) void gemm_fused12(
    const u16* __restrict__ Xb, const u16* __restrict__ Xsq,
    const u16* __restrict__ W1th, const u16* __restrict__ Pth,
    const float* __restrict__ b1a, const float* __restrict__ cvec,
    u16* __restrict__ Hout) {
  extern __shared__ char smem[];
  const int tid = threadIdx.x;
  const int l = tid & 63;
  const int w = tid >> 6;
  const int wm = w & 1, wn = w >> 1;
  const int lr = l & 15, lk = l >> 4;
  const int sx = lr & 7;
  const int bid = blockIdx.x;
  const int L = (bid & 7) * 128 + (bid >> 3);
  const int p = L >> 3;
  const int g = ((L >> 2) & 1) ^ 1;
  const int n = L & 3;
  const int m0 = p * 128, n0 = n * 128;
  const int Kg = g ? 1024 : 512;
  const int nt = g ? 16 : 8;
  const u16* Bmat = g ? Pth : W1th;
  const int srow = l >> 3;
  const int sslot = (l & 7) ^ srow;

  f32x4 acc[4][4];
#pragma unroll
  for (int i = 0; i < 4; ++i)
#pragma unroll
    for (int j = 0; j < 4; ++j) acc[i][j] = (f32x4){0.f, 0.f, 0.f, 0.f};

#define F12_STAGE(buf, k0)                                                    \
  {                                                                           \
    const u16* Asrc = g ? (((k0) < 512) ? Xsq : Xb) : Xb;                     \
    const int kb = (k0)&511;                                                  \
    char* dA = smem + (buf)*16384;                                            \
    char* dB = smem + 32768 + (buf)*16384;                                    \
    _Pragma("unroll") for (int pp = 0; pp < 4; ++pp) {                        \
      int c = pp * 4 + w;                                                     \
      int row = c * 8 + srow;                                                 \
      int loff = c * 1024;                                                    \
      size_t goa = (size_t)(m0 + row) * 512 + kb + sslot * 8;                 \
      size_t gob = (size_t)(n0 + row) * Kg + (k0) + sslot * 8;                \
      __builtin_amdgcn_global_load_lds(                                       \
          (const __attribute__((address_space(1))) void*)(Asrc + goa),        \
          (__attribute__((address_space(3))) void*)(dA + loff), 16, 0, 0);    \
      __builtin_amdgcn_global_load_lds(                                       \
          (const __attribute__((address_space(1))) void*)(Bmat + gob),        \
          (__attribute__((address_space(3))) void*)(dB + loff), 16, 0, 0);    \
    }                                                                         \
  }

  F12_STAGE(0, 0);
  F12_STAGE(1, 64);
  for (int t = 0; t < nt; ++t) {
    if (t + 1 < nt) {
      wait_vm8();
    } else {
      wait_vm0();
    }
    sgb0();
    sbar();
    sgb0();
    const char* sA = smem + (t & 1) * 16384;
    const char* sB = smem + 32768 + (t & 1) * 16384;
#pragma unroll
    for (int ks = 0; ks < 2; ++ks) {
      bf16x8 av[4], bv[4];
#pragma unroll
      for (int i = 0; i < 4; ++i)
        av[i] = *(const bf16x8*)(sA + (wm * 64 + i * 16 + lr) * 128 +
                                 (((ks * 4 + lk) ^ sx) * 16));
#pragma unroll
      for (int j = 0; j < 4; ++j)
        bv[j] = *(const bf16x8*)(sB + (wn * 64 + j * 16 + lr) * 128 +
                                 (((ks * 4 + lk) ^ sx) * 16));
#pragma unroll
      for (int i = 0; i < 4; ++i)
#pragma unroll
        for (int j = 0; j < 4; ++j)
          acc[i][j] = __builtin_amdgcn_mfma_f32_16x16x32_bf16(av[i], bv[j],
                                                              acc[i][j], 0, 0, 0);
    }
    sgb0();
    sbar();
    sgb0();
    if (t + 2 < nt) F12_STAGE(t & 1, (t + 2) * 64);
  }
#undef F12_STAGE

  const int mwb = m0 + wm * 64;
  const int nwb = n0 + wn * 64;
  const float* bias = g ? cvec : b1a;
#pragma unroll
  for (int j = 0; j < 4; ++j) {
    int nn = nwb + j * 16 + lr;
    float bv = bias[nn];
#pragma unroll
    for (int i = 0; i < 4; ++i) {
#pragma unroll
      for (int r = 0; r < 4; ++r) {
        int m = mwb + i * 16 + lk * 4 + r;
        float v = acc[i][j][r] + bv;
        v = g ? fmaxf(1.f - v, 0.f) : fmaxf(v, 0.f);
        Hout[(size_t)m * 1024 + g * 512 + nn] = f2bf(v);
      }
    }
  }
}

// G3 + fused sparsemax. BM=64 x BN=512(full row) x BK=64, 512 threads
// (8 waves, wave w owns cols [w*64, w*64+64)), static LDS 144KB:
// A[2]@0/8K (64x64 bf16), B[2]@16K/80K (512x64 bf16). Counted-vmcnt 2-ahead
// pipeline (9 loads/thread/stage -> vmcnt(9)). After the K-loop each block
// holds 64 complete rows of pre in registers -> Newton sparsemax in-block
// (16-lane shuffle partials -> LDS [64][8] -> wave-0 tau update, 20 fixed
// iters; tau monotone from max-1, update exact at convergence), write mask.
// Grid 256 = 1 block/CU; XCD swizzle q=(bid&7)*32+(bid>>3).
__global__ __launch_bounds__(512, 1) void gemm3_sm(
    const u16* __restrict__ Ah, const u16* __restrict__ Bh,
    const float* __restrict__ bias, const float* __restrict__ xorig,
    const float* __restrict__ wadd, float* __restrict__ outp) {
  __shared__ char smem[147456];
  const int tid = threadIdx.x;
  const int l = tid & 63;
  const int w = tid >> 6;  // 0..7, wave = n-range
  const int lr = l & 15, lk = l >> 4;
  const int sx = lr & 7;
  const int bid = blockIdx.x;
  const int q = (bid & 7) * 32 + (bid >> 3);
  const int m0 = q * 64;
  const int srow = l >> 3;
  const int sslot = (l & 7) ^ srow;

  f32x4 acc[4][4];
#pragma unroll
  for (int i = 0; i < 4; ++i)
#pragma unroll
    for (int j = 0; j < 4; ++j) acc[i][j] = (f32x4){0.f, 0.f, 0.f, 0.f};

#define G3S_STAGE(buf, k0)                                                    \
  {                                                                           \
    char* dA = smem + (buf)*8192;                                             \
    char* dB = smem + 16384 + (buf)*65536;                                    \
    {                                                                         \
      int row = w * 8 + srow;                                                 \
      size_t goa = (size_t)(m0 + row) * 1024 + (k0) + sslot * 8;              \
      __builtin_amdgcn_global_load_lds(                                       \
          (const __attribute__((address_space(1))) void*)(Ah + goa),          \
          (__attribute__((address_space(3))) void*)(dA + w * 1024), 16, 0, 0);\
    }                                                                         \
    _Pragma("unroll") for (int pp = 0; pp < 8; ++pp) {                        \
      int c = pp * 8 + w;                                                     \
      int row = c * 8 + srow;                                                 \
      size_t gob = (size_t)row * 1024 + (k0) + sslot * 8;                     \
      __builtin_amdgcn_global_load_lds(                                       \
          (const __attribute__((address_space(1))) void*)(Bh + gob),          \
          (__attribute__((address_space(3))) void*)(dB + c * 1024), 16, 0, 0);\
    }                                                                         \
  }

  G3S_STAGE(0, 0);
  G3S_STAGE(1, 64);
  for (int t = 0; t < 16; ++t) {
    if (t + 1 < 16) {
      wait_vm9();
    } else {
      wait_vm0();
    }
    sgb0();
    sbar();
    sgb0();
    const char* sA = smem + (t & 1) * 8192;
    const char* sB = smem + 16384 + (t & 1) * 65536;
#pragma unroll
    for (int ks = 0; ks < 2; ++ks) {
      bf16x8 av[4], bv[4];
#pragma unroll
      for (int i = 0; i < 4; ++i)
        av[i] = *(const bf16x8*)(sA + (i * 16 + lr) * 128 +
                                 (((ks * 4 + lk) ^ sx) * 16));
#pragma unroll
      for (int j = 0; j < 4; ++j)
        bv[j] = *(const bf16x8*)(sB + (w * 64 + j * 16 + lr) * 128 +
                                 (((ks * 4 + lk) ^ sx) * 16));
#pragma unroll
      for (int i = 0; i < 4; ++i)
#pragma unroll
        for (int j = 0; j < 4; ++j)
          acc[i][j] = __builtin_amdgcn_mfma_f32_16x16x32_bf16(av[i], bv[j],
                                                              acc[i][j], 0, 0, 0);
    }
    sgb0();
    sbar();
    sgb0();
    if (t + 2 < 16) G3S_STAGE(t & 1, (t + 2) * 64);
  }
#undef G3S_STAGE

  // ---- epilogue: pre = w0*x + w1*relu(acc+bias); in-block sparsemax ----
  __syncthreads();  // full drain; LDS reusable
  float* mPart = (float*)smem;              // [64][8]
  float* sPart = (float*)(smem + 2048);     // [64][8]
  float* kPart = (float*)(smem + 4096);     // [64][8]
  float* tauLds = (float*)(smem + 6144);    // [64]
  const float w0 = wadd[0], w1 = wadd[1];

#pragma unroll
  for (int j = 0; j < 4; ++j) {
    int col = w * 64 + j * 16 + lr;
    float bv = bias[col];
#pragma unroll
    for (int i = 0; i < 4; ++i) {
#pragma unroll
      for (int r = 0; r < 4; ++r) {
        int m = m0 + i * 16 + lk * 4 + r;
        float v = fmaxf(acc[i][j][r] + bv, 0.f);
        acc[i][j][r] = fmaf(w1, v, w0 * xorig[(size_t)m * 512 + col]);
      }
    }
  }
  // per-(i,r) max over j, then over the 16-lane lr group
  float mx[4][4];
#pragma unroll
  for (int i = 0; i < 4; ++i)
#pragma unroll
    for (int r = 0; r < 4; ++r) {
      float m = acc[i][0][r];
#pragma unroll
      for (int j = 1; j < 4; ++j) m = fmaxf(m, acc[i][j][r]);
      mx[i][r] = m;
    }
#pragma unroll
  for (int off = 1; off < 16; off <<= 1)
#pragma unroll
    for (int i = 0; i < 4; ++i)
#pragma unroll
      for (int r = 0; r < 4; ++r)
        mx[i][r] = fmaxf(mx[i][r], __shfl_xor(mx[i][r], off));
  if (lr == 0) {
#pragma unroll
    for (int i = 0; i < 4; ++i)
#pragma unroll
      for (int r = 0; r < 4; ++r)
        mPart[(i * 16 + lk * 4 + r) * 8 + w] = mx[i][r];
  }
  __syncthreads();
  if (tid < 64) {
    float m = mPart[tid * 8];
#pragma unroll
    for (int e = 1; e < 8; ++e) m = fmaxf(m, mPart[tid * 8 + e]);
    tauLds[tid] = m - 1.0f;
  }
  __syncthreads();

  for (int it = 0; it < 20; ++it) {
    float sl[4][4], kl[4][4];
#pragma unroll
    for (int i = 0; i < 4; ++i)
#pragma unroll
      for (int r = 0; r < 4; ++r) {
        float tau = tauLds[i * 16 + lk * 4 + r];
        float s = 0.f, k = 0.f;
#pragma unroll
        for (int j = 0; j < 4; ++j) {
          float v = acc[i][j][r];
          if (v > tau) {
            s += v;
            k += 1.f;
          }
        }
        sl[i][r] = s;
        kl[i][r] = k;
      }
#pragma unroll
    for (int off = 1; off < 16; off <<= 1)
#pragma unroll
      for (int i = 0; i < 4; ++i)
#pragma unroll
        for (int r = 0; r < 4; ++r) {
          sl[i][r] += __shfl_xor(sl[i][r], off);
          kl[i][r] += __shfl_xor(kl[i][r], off);
        }
    if (lr == 0) {
#pragma unroll
      for (int i = 0; i < 4; ++i)
#pragma unroll
        for (int r = 0; r < 4; ++r) {
          int row = i * 16 + lk * 4 + r;
          sPart[row * 8 + w] = sl[i][r];
          kPart[row * 8 + w] = kl[i][r];
        }
    }
    __syncthreads();
    if (tid < 64) {
      float S = 0.f, K = 0.f;
#pragma unroll
      for (int e = 0; e < 8; ++e) {
        S += sPart[tid * 8 + e];
        K += kPart[tid * 8 + e];
      }
      tauLds[tid] = (S - 1.f) / K;  // K >= 1 always (tau < row max)
    }
    __syncthreads();
  }

#pragma unroll
  for (int i = 0; i < 4; ++i)
#pragma unroll
    for (int r = 0; r < 4; ++r) {
      int row = i * 16 + lk * 4 + r;
      float tau = tauLds[row];
      int m = m0 + row;
#pragma unroll
      for (int j = 0; j < 4; ++j) {
        int col = w * 64 + j * 16 + lr;
        outp[(size_t)m * 512 + col] = fmaxf(acc[i][j][r] - tau, 0.f);
      }
    }
}

extern "C" void kernel_launch(void* const* d_in, const int* in_sizes, int n_in,
                              void* d_out, int out_size, void* d_ws,
                              size_t ws_size, hipStream_t stream) {
  const float* x = (const float*)d_in[0];
  const float* W1 = (const float*)d_in[1];
  const float* b1 = (const float*)d_in[2];
  const float* centers = (const float*)d_in[3];
  const float* coefs = (const float*)d_in[4];
  const float* gamma = (const float*)d_in[5];
  const float* beta = (const float*)d_in[6];
  const float* mean = (const float*)d_in[7];
  const float* var = (const float*)d_in[8];
  const float* W_out = (const float*)d_in[9];
  const float* b_out = (const float*)d_in[10];
  const float* wadd = (const float*)d_in[11];
  float* out = (float*)d_out;

  // Layout within the round-1-proven 69,212,160 B floor:
  char* ws = (char*)d_ws;
  u16* Hh = (u16*)(ws);                      // [16384][1024] bf16 = 32 MB
  float* b1a = (float*)(ws + 33554432);      // 2 KB
  u16* Wth = (u16*)(ws + 33562624);          // [512][1024] bf16 = 1 MB
  u16* Xb = (u16*)(ws + 50331648);           // [16384][512] bf16 = 16 MB
  char* pool = ws + 67108864;                // 2 MB
  u16* W1th = (u16*)(pool);                  // [512][512] bf16 = 0.5 MB
  u16* Pth = (u16*)(pool + 1048576);         // [512][1024] bf16 = 1 MB
  float* cvec = (float*)(ws + 69206016);     // 2 KB
  // Xsq lives in d_out (32 MB fp32): dead scratch until gemm3_sm overwrites.
  u16* Xsq = (u16*)d_out;

  prep_all_kernel<<<5384, 256, 0, stream>>>(x, W1, b1, centers, coefs, gamma,
                                            beta, mean, var, W_out, Xb, Xsq,
                                            Pth, cvec, W1th, Wth, b1a);

  gemm_fused12<<<1024, 256, 65536, stream>>>(Xb, Xsq, W1th, Pth, b1a, cvec,
                                             Hh);
  gemm3_sm<<<256, 512, 0, stream>>>(Hh, Wth, b_out, x, wadd, out);
}

// Round 15
// 106.294 us; speedup vs baseline: 1.6534x; 1.6534x over previous
//
#include <hip/hip_runtime.h>
#include <math.h>

typedef float f4 __attribute__((ext_vector_type(4)));
typedef float f32x4 __attribute__((ext_vector_type(4)));
typedef __bf16 bf16x8 __attribute__((ext_vector_type(8)));
typedef unsigned short u16;
typedef u16 us8 __attribute__((ext_vector_type(8)));

__device__ __forceinline__ u16 f2bf(float f) {
  unsigned u = __builtin_bit_cast(unsigned, f);
  unsigned r = u + 0x7fffu + ((u >> 16) & 1u);
  return (u16)(r >> 16);
}
__device__ __forceinline__ float bf2f(u16 h) {
  unsigned u = ((unsigned)h) << 16;
  return __builtin_bit_cast(float, u);
}

// scale[d] = rsqrt(var+eps)*gamma ; shift[d] = beta - mean*scale
__global__ __launch_bounds__(256) void prep_bn_kernel(
    const float* __restrict__ gamma, const float* __restrict__ beta,
    const float* __restrict__ mean, const float* __restrict__ var,
    float* __restrict__ scale, float* __restrict__ shift) {
  int d = blockIdx.x * blockDim.x + threadIdx.x;
  if (d < 512) {
    float s = rsqrtf(var[d] + 1e-3f) * gamma[d];
    scale[d] = s;
    shift[d] = beta[d] - mean[d] * s;
  }
}

// Pth[j][k] (bf16, [512][1024]): k<512 -> coefs^2 ; k>=512 -> -2*coefs^2*centers
// cvec[j] = sum_d coefs^2*centers^2  (fp32)
__global__ __launch_bounds__(64) void prep_params_kernel(
    const float* __restrict__ coefs, const float* __restrict__ centers,
    u16* __restrict__ pth, float* __restrict__ cvec) {
  int j = blockIdx.x;
  int l = threadIdx.x;
  int d0 = l * 8;
  f4 c0 = *(const f4*)(coefs + (size_t)j * 512 + d0);
  f4 c1 = *(const f4*)(coefs + (size_t)j * 512 + d0 + 4);
  f4 e0 = *(const f4*)(centers + (size_t)j * 512 + d0);
  f4 e1 = *(const f4*)(centers + (size_t)j * 512 + d0 + 4);
  us8 pa, pb;
  float acc = 0.f;
#pragma unroll
  for (int e = 0; e < 8; ++e) {
    float cf = (e < 4) ? c0[e] : c1[e - 4];
    float ce = (e < 4) ? e0[e] : e1[e - 4];
    float a = cf * cf;
    pa[e] = f2bf(a);
    pb[e] = f2bf(-2.f * a * ce);
    acc = fmaf(a * ce, ce, acc);
  }
  *(us8*)(pth + (size_t)j * 1024 + d0) = pa;
  *(us8*)(pth + (size_t)j * 1024 + 512 + d0) = pb;
#pragma unroll
  for (int off = 32; off; off >>= 1) acc += __shfl_xor(acc, off);
  if (l == 0) cvec[j] = acc;
}

// Transpose [K][N] fp32 -> Th [N][K] bf16 (hi only)
__global__ __launch_bounds__(256) void transpose_split_kernel(
    const float* __restrict__ in, u16* __restrict__ th, int K, int N) {
  __shared__ float t[32][33];
  int lx = threadIdx.x;  // 32
  int ly = threadIdx.y;  // 8
  int n0 = blockIdx.x * 32, k0 = blockIdx.y * 32;
#pragma unroll
  for (int i = 0; i < 4; ++i)
    t[ly + 8 * i][lx] = in[(size_t)(k0 + ly + 8 * i) * N + n0 + lx];
  __syncthreads();
#pragma unroll
  for (int i = 0; i < 4; ++i) {
    float v = t[lx][ly + 8 * i];
    th[(size_t)(n0 + ly + 8 * i) * K + k0 + lx] = f2bf(v);
  }
}

// x [16384][512] fp32 -> Xh = bf16(x), Xb = bf16(xb), Xsq = bf16(xb*xb)
__global__ __launch_bounds__(256) void conv_x_kernel(
    const float* __restrict__ x, const float* __restrict__ scale,
    const float* __restrict__ shift, u16* __restrict__ xh,
    u16* __restrict__ xb, u16* __restrict__ xsq) {
  int gid = blockIdx.x * 256 + threadIdx.x;
  int m = gid >> 6;
  int d0 = (gid & 63) * 8;
  f4 v0 = *(const f4*)(x + (size_t)m * 512 + d0);
  f4 v1 = *(const f4*)(x + (size_t)m * 512 + d0 + 4);
  f4 s0 = *(const f4*)(scale + d0);
  f4 s1 = *(const f4*)(scale + d0 + 4);
  f4 h0 = *(const f4*)(shift + d0);
  f4 h1 = *(const f4*)(shift + d0 + 4);
  us8 oh, ob, oq;
#pragma unroll
  for (int e = 0; e < 8; ++e) {
    float xv = (e < 4) ? v0[e] : v1[e - 4];
    float sc = (e < 4) ? s0[e] : s1[e - 4];
    float sh = (e < 4) ? h0[e] : h1[e - 4];
    oh[e] = f2bf(xv);
    float xbf = fmaf(xv, sc, sh);
    ob[e] = f2bf(xbf);
    oq[e] = f2bf(xbf * xbf);
  }
  *(us8*)(xh + (size_t)m * 512 + d0) = oh;
  *(us8*)(xb + (size_t)m * 512 + d0) = ob;
  *(us8*)(xsq + (size_t)m * 512 + d0) = oq;
}

__device__ __forceinline__ void wait_vm8() {
  asm volatile("s_waitcnt vmcnt(8)" ::: "memory");
}
__device__ __forceinline__ void wait_vm0() {
  asm volatile("s_waitcnt vmcnt(0)" ::: "memory");
}
__device__ __forceinline__ void sbar() { __builtin_amdgcn_s_barrier(); }
__device__ __forceinline__ void sgb0() { __builtin_amdgcn_sched_barrier(0); }

// Merged G1+G2, counted-vmcnt 2-tile-ahead pipeline (T4): raw s_barrier, no
// vmcnt(0) drain in the main loop. 1024 blocks, 128x128, BK=64. LDS 64KB.
// Per STAGE: 8 global_load_lds/thread. Prologue stages tiles 0,1 (16 in
// flight); iter t: vmcnt(8) [t done, t+1 flying]; barrier; MFMA on buf(t&1);
// barrier; stage t+2 into buf(t&1).
__global__ __launch_bounds__(256, 2) void gemm_fused12(
    const u16* __restrict__ Xh, const u16* __restrict__ Xb,
    const u16* __restrict__ Xsq, const u16* __restrict__ W1th,
    const u16* __restrict__ Pth, const float* __restrict__ b1,
    const float* __restrict__ cvec, u16* __restrict__ Hout) {
  extern __shared__ char smem[];
  const int tid = threadIdx.x;
  const int l = tid & 63;
  const int w = tid >> 6;
  const int wm = w & 1, wn = w >> 1;
  const int lr = l & 15, lk = l >> 4;
  const int sx = lr & 7;
  const int bid = blockIdx.x;
  const int L = (bid & 7) * 128 + (bid >> 3);
  const int p = L >> 3;
  const int g = ((L >> 2) & 1) ^ 1;
  const int n = L & 3;
  const int m0 = p * 128, n0 = n * 128;
  const int Kg = g ? 1024 : 512;
  const int nt = g ? 16 : 8;
  const u16* Bmat = g ? Pth : W1th;
  const int srow = l >> 3;
  const int sslot = (l & 7) ^ srow;

  f32x4 acc[4][4];
#pragma unroll
  for (int i = 0; i < 4; ++i)
#pragma unroll
    for (int j = 0; j < 4; ++j) acc[i][j] = (f32x4){0.f, 0.f, 0.f, 0.f};

#define F12_STAGE(buf, k0)                                                    \
  {                                                                           \
    const u16* Asrc = g ? (((k0) < 512) ? Xsq : Xb) : Xh;                     \
    const int kb = (k0)&511;                                                  \
    char* dA = smem + (buf)*16384;                                            \
    char* dB = smem + 32768 + (buf)*16384;                                    \
    _Pragma("unroll") for (int pp = 0; pp < 4; ++pp) {                        \
      int c = pp * 4 + w;                                                     \
      int row = c * 8 + srow;                                                 \
      int loff = c * 1024;                                                    \
      size_t goa = (size_t)(m0 + row) * 512 + kb + sslot * 8;                 \
      size_t gob = (size_t)(n0 + row) * Kg + (k0) + sslot * 8;                \
      __builtin_amdgcn_global_load_lds(                                       \
          (const __attribute__((address_space(1))) void*)(Asrc + goa),        \
          (__attribute__((address_space(3))) void*)(dA + loff), 16, 0, 0);    \
      __builtin_amdgcn_global_load_lds(                                       \
          (const __attribute__((address_space(1))) void*)(Bmat + gob),        \
          (__attribute__((address_space(3))) void*)(dB + loff), 16, 0, 0);    \
    }                                                                         \
  }

  F12_STAGE(0, 0);
  F12_STAGE(1, 64);
  for (int t = 0; t < nt; ++t) {
    if (t + 1 < nt) {
      wait_vm8();
    } else {
      wait_vm0();
    }
    sgb0();
    sbar();
    sgb0();
    const char* sA = smem + (t & 1) * 16384;
    const char* sB = smem + 32768 + (t & 1) * 16384;
#pragma unroll
    for (int ks = 0; ks < 2; ++ks) {
      bf16x8 av[4], bv[4];
#pragma unroll
      for (int i = 0; i < 4; ++i)
        av[i] = *(const bf16x8*)(sA + (wm * 64 + i * 16 + lr) * 128 +
                                 (((ks * 4 + lk) ^ sx) * 16));
#pragma unroll
      for (int j = 0; j < 4; ++j)
        bv[j] = *(const bf16x8*)(sB + (wn * 64 + j * 16 + lr) * 128 +
                                 (((ks * 4 + lk) ^ sx) * 16));
#pragma unroll
      for (int i = 0; i < 4; ++i)
#pragma unroll
        for (int j = 0; j < 4; ++j)
          acc[i][j] = __builtin_amdgcn_mfma_f32_16x16x32_bf16(av[i], bv[j],
                                                              acc[i][j], 0, 0, 0);
    }
    sgb0();
    sbar();
    sgb0();
    if (t + 2 < nt) F12_STAGE(t & 1, (t + 2) * 64);
  }
#undef F12_STAGE

  const int mwb = m0 + wm * 64;
  const int nwb = n0 + wn * 64;
  const float* bias = g ? cvec : b1;
#pragma unroll
  for (int j = 0; j < 4; ++j) {
    int nn = nwb + j * 16 + lr;
    float bv = bias[nn];
#pragma unroll
    for (int i = 0; i < 4; ++i) {
#pragma unroll
      for (int r = 0; r < 4; ++r) {
        int m = mwb + i * 16 + lk * 4 + r;
        float v = acc[i][j][r] + bv;
        v = g ? fmaxf(1.f - v, 0.f) : fmaxf(v, 0.f);
        Hout[(size_t)m * 1024 + g * 512 + nn] = f2bf(v);
      }
    }
  }
}

// G3: out = w0*x + w1*relu(Hh @ Wth^T + b_out). K=1024, counted-vmcnt 2-ahead
// pipeline, LDS 64KB. 512 blocks, XCD swizzle.
__global__ __launch_bounds__(256, 2) void gemm3(
    const u16* __restrict__ Ah, const u16* __restrict__ Bh,
    const float* __restrict__ bias, const float* __restrict__ xorig,
    const float* __restrict__ wadd, float* __restrict__ outp) {
  extern __shared__ char smem[];
  const int tid = threadIdx.x;
  const int l = tid & 63;
  const int w = tid >> 6;
  const int wm = w & 1, wn = w >> 1;
  const int lr = l & 15, lk = l >> 4;
  const int sx = lr & 7;
  const int bid = blockIdx.x;
  const int lin = (bid & 7) * 64 + (bid >> 3);
  const int m0 = (lin >> 2) * 128, n0 = (lin & 3) * 128;
  const int srow = l >> 3;
  const int sslot = (l & 7) ^ srow;

  f32x4 acc[4][4];
#pragma unroll
  for (int i = 0; i < 4; ++i)
#pragma unroll
    for (int j = 0; j < 4; ++j) acc[i][j] = (f32x4){0.f, 0.f, 0.f, 0.f};

#define G3_STAGE(buf, k0)                                                     \
  {                                                                           \
    char* dA = smem + (buf)*16384;                                            \
    char* dB = smem + 32768 + (buf)*16384;                                    \
    _Pragma("unroll") for (int pp = 0; pp < 4; ++pp) {                        \
      int c = pp * 4 + w;                                                     \
      int row = c * 8 + srow;                                                 \
      int loff = c * 1024;                                                    \
      size_t gob = (size_t)(n0 + row) * 1024 + (k0) + sslot * 8;              \
      size_t goa = (size_t)(m0 + row) * 1024 + (k0) + sslot * 8;              \
      __builtin_amdgcn_global_load_lds(                                       \
          (const __attribute__((address_space(1))) void*)(Bh + gob),          \
          (__attribute__((address_space(3))) void*)(dB + loff), 16, 0, 0);    \
      __builtin_amdgcn_global_load_lds(                                       \
          (const __attribute__((address_space(1))) void*)(Ah + goa),          \
          (__attribute__((address_space(3))) void*)(dA + loff), 16, 0, 0);    \
    }                                                                         \
  }

  G3_STAGE(0, 0);
  G3_STAGE(1, 64);
  for (int t = 0; t < 16; ++t) {
    if (t + 1 < 16) {
      wait_vm8();
    } else {
      wait_vm0();
    }
    sgb0();
    sbar();
    sgb0();
    const char* sA = smem + (t & 1) * 16384;
    const char* sB = smem + 32768 + (t & 1) * 16384;
#pragma unroll
    for (int ks = 0; ks < 2; ++ks) {
      bf16x8 av[4], bv[4];
#pragma unroll
      for (int i = 0; i < 4; ++i)
        av[i] = *(const bf16x8*)(sA + (wm * 64 + i * 16 + lr) * 128 +
                                 (((ks * 4 + lk) ^ sx) * 16));
#pragma unroll
      for (int j = 0; j < 4; ++j)
        bv[j] = *(const bf16x8*)(sB + (wn * 64 + j * 16 + lr) * 128 +
                                 (((ks * 4 + lk) ^ sx) * 16));
#pragma unroll
      for (int i = 0; i < 4; ++i)
#pragma unroll
        for (int j = 0; j < 4; ++j)
          acc[i][j] = __builtin_amdgcn_mfma_f32_16x16x32_bf16(av[i], bv[j],
                                                              acc[i][j], 0, 0, 0);
    }
    sgb0();
    sbar();
    sgb0();
    if (t + 2 < 16) G3_STAGE(t & 1, (t + 2) * 64);
  }
#undef G3_STAGE

  const int mwb = m0 + wm * 64;
  const int nwb = n0 + wn * 64;
  float w0 = wadd[0], w1 = wadd[1];
#pragma unroll
  for (int j = 0; j < 4; ++j) {
    int n = nwb + j * 16 + lr;
    float bv = bias[n];
#pragma unroll
    for (int i = 0; i < 4; ++i) {
#pragma unroll
      for (int r = 0; r < 4; ++r) {
        int m = mwb + i * 16 + lk * 4 + r;
        float v = fmaxf(acc[i][j][r] + bv, 0.f);
        outp[(size_t)m * 512 + n] = fmaf(w1, v, w0 * xorig[(size_t)m * 512 + n]);
      }
    }
  }
}

// One wave per row of 512. XCD-aligned work swizzle: rows are read on the
// XCD whose L2 holds them from gemm3's write (G3 panel p -> XCD p/16).
__global__ __launch_bounds__(256) void sparsemax_kernel(float* __restrict__ out) {
  int wrk = (blockIdx.x & 7) * 512 + (blockIdx.x >> 3);
  int row = wrk * 4 + (threadIdx.x >> 6);
  int lane = threadIdx.x & 63;
  float* rp = out + (size_t)row * 512;
  f4 z0 = *(const f4*)(rp + lane * 8);
  f4 z1 = *(const f4*)(rp + lane * 8 + 4);
  float z[8];
#pragma unroll
  for (int e = 0; e < 4; ++e) {
    z[e] = z0[e];
    z[4 + e] = z1[e];
  }
  float m = z[0];
#pragma unroll
  for (int i = 1; i < 8; ++i) m = fmaxf(m, z[i]);
#pragma unroll
  for (int off = 32; off; off >>= 1) m = fmaxf(m, __shfl_xor(m, off));
  float tau = m - 1.0f;
  for (int it = 0; it < 32; ++it) {
    float s = 0.f, k = 0.f;
#pragma unroll
    for (int i = 0; i < 8; ++i) {
      if (z[i] > tau) {
        s += z[i] - tau;
        k += 1.f;
      }
    }
#pragma unroll
    for (int off = 32; off; off >>= 1) {
      s += __shfl_xor(s, off);
      k += __shfl_xor(k, off);
    }
    if (k < 0.5f) break;
    float tn = tau + (s - 1.f) / k;
    if (tn == tau) break;
    tau = tn;
  }
  float s = 0.f, k = 0.f;
#pragma unroll
  for (int i = 0; i < 8; ++i)
    if (z[i] > tau) {
      s += z[i];
      k += 1.f;
    }
#pragma unroll
  for (int off = 32; off; off >>= 1) {
    s += __shfl_xor(s, off);
    k += __shfl_xor(k, off);
  }
  float tauf = (k >= 0.5f) ? (s - 1.f) / k : (m - 1.f);
  f4 o0, o1;
#pragma unroll
  for (int e = 0; e < 4; ++e) {
    o0[e] = fmaxf(z[e] - tauf, 0.f);
    o1[e] = fmaxf(z[4 + e] - tauf, 0.f);
  }
  *(f4*)(rp + lane * 8) = o0;
  *(f4*)(rp + lane * 8 + 4) = o1;
}

extern "C" void kernel_launch(void* const* d_in, const int* in_sizes, int n_in,
                              void* d_out, int out_size, void* d_ws,
                              size_t ws_size, hipStream_t stream) {
  const float* x = (const float*)d_in[0];
  const float* W1 = (const float*)d_in[1];
  const float* b1 = (const float*)d_in[2];
  const float* centers = (const float*)d_in[3];
  const float* coefs = (const float*)d_in[4];
  const float* gamma = (const float*)d_in[5];
  const float* beta = (const float*)d_in[6];
  const float* mean = (const float*)d_in[7];
  const float* var = (const float*)d_in[8];
  const float* W_out = (const float*)d_in[9];
  const float* b_out = (const float*)d_in[10];
  const float* wadd = (const float*)d_in[11];
  float* out = (float*)d_out;

  // Base layout: 69,212,160 B == round-1-proven ws_size floor.
  char* ws = (char*)d_ws;
  u16* Hh = (u16*)(ws);                      // [16384][1024] bf16 = 32 MB
  u16* Xh = (u16*)(ws + 33554432);           // [16384][512]  bf16 = 16 MB
  u16* Xb = (u16*)(ws + 50331648);           // [16384][512]  bf16 = 16 MB
  char* pool = ws + 67108864;                // 2 MB
  u16* W1th = (u16*)(pool);
  u16* Pth = (u16*)(pool + 1048576);
  float* cvec = (float*)(ws + 69206016);     // 2 KB
  float* scale = (float*)(ws + 69208064);    // 2 KB
  float* shift = (float*)(ws + 69210112);    // 2 KB
  // Xsq lives in d_out (32 MB fp32): dead scratch until gemm3 overwrites it.
  u16* Xsq = (u16*)d_out;
  const bool bigws = (ws_size >= (size_t)70260736);
  u16* Wth = bigws ? (u16*)(ws + 69212160) : (u16*)(pool);

  prep_bn_kernel<<<2, 256, 0, stream>>>(gamma, beta, mean, var, scale, shift);
  prep_params_kernel<<<512, 64, 0, stream>>>(coefs, centers, Pth, cvec);
  transpose_split_kernel<<<dim3(16, 16), dim3(32, 8), 0, stream>>>(W1, W1th,
                                                                   512, 512);
  if (bigws) {
    transpose_split_kernel<<<dim3(16, 32), dim3(32, 8), 0, stream>>>(
        W_out, Wth, 1024, 512);
  }
  conv_x_kernel<<<4096, 256, 0, stream>>>(x, scale, shift, Xh, Xb, Xsq);

  gemm_fused12<<<1024, 256, 65536, stream>>>(Xh, Xb, Xsq, W1th, Pth, b1, cvec,
                                             Hh);

  if (!bigws) {
    transpose_split_kernel<<<dim3(16, 32), dim3(32, 8), 0, stream>>>(
        W_out, Wth, 1024, 512);
  }
  gemm3<<<512, 256, 65536, stream>>>(Hh, Wth, b_out, x, wadd, out);
  sparsemax_kernel<<<4096, 256, 0, stream>>>(out);
}

// Round 16
// 104.263 us; speedup vs baseline: 1.6857x; 1.0195x over previous
//
#include <hip/hip_runtime.h>
#include <math.h>

typedef float f4 __attribute__((ext_vector_type(4)));
typedef float f32x4 __attribute__((ext_vector_type(4)));
typedef __bf16 bf16x8 __attribute__((ext_vector_type(8)));
typedef unsigned short u16;
typedef u16 us8 __attribute__((ext_vector_type(8)));

__device__ __forceinline__ u16 f2bf(float f) {
  unsigned u = __builtin_bit_cast(unsigned, f);
  unsigned r = u + 0x7fffu + ((u >> 16) & 1u);
  return (u16)(r >> 16);
}
__device__ __forceinline__ float bf2f(u16 h) {
  unsigned u = ((unsigned)h) << 16;
  return __builtin_bit_cast(float, u);
}

// scale[d] = rsqrt(var+eps)*gamma ; shift[d] = beta - mean*scale
__global__ __launch_bounds__(256) void prep_bn_kernel(
    const float* __restrict__ gamma, const float* __restrict__ beta,
    const float* __restrict__ mean, const float* __restrict__ var,
    float* __restrict__ scale, float* __restrict__ shift) {
  int d = blockIdx.x * blockDim.x + threadIdx.x;
  if (d < 512) {
    float s = rsqrtf(var[d] + 1e-3f) * gamma[d];
    scale[d] = s;
    shift[d] = beta[d] - mean[d] * s;
  }
}

// Pth[j][k] (bf16, [512][1024]): k<512 -> coefs^2 ; k>=512 -> -2*coefs^2*centers
// cvec[j] = sum_d coefs^2*centers^2  (fp32)
__global__ __launch_bounds__(64) void prep_params_kernel(
    const float* __restrict__ coefs, const float* __restrict__ centers,
    u16* __restrict__ pth, float* __restrict__ cvec) {
  int j = blockIdx.x;
  int l = threadIdx.x;
  int d0 = l * 8;
  f4 c0 = *(const f4*)(coefs + (size_t)j * 512 + d0);
  f4 c1 = *(const f4*)(coefs + (size_t)j * 512 + d0 + 4);
  f4 e0 = *(const f4*)(centers + (size_t)j * 512 + d0);
  f4 e1 = *(const f4*)(centers + (size_t)j * 512 + d0 + 4);
  us8 pa, pb;
  float acc = 0.f;
#pragma unroll
  for (int e = 0; e < 8; ++e) {
    float cf = (e < 4) ? c0[e] : c1[e - 4];
    float ce = (e < 4) ? e0[e] : e1[e - 4];
    float a = cf * cf;
    pa[e] = f2bf(a);
    pb[e] = f2bf(-2.f * a * ce);
    acc = fmaf(a * ce, ce, acc);
  }
  *(us8*)(pth + (size_t)j * 1024 + d0) = pa;
  *(us8*)(pth + (size_t)j * 1024 + 512 + d0) = pb;
#pragma unroll
  for (int off = 32; off; off >>= 1) acc += __shfl_xor(acc, off);
  if (l == 0) cvec[j] = acc;
}

// Transpose [K][N] fp32 -> Th [N][K] bf16 (hi only)
__global__ __launch_bounds__(256) void transpose_split_kernel(
    const float* __restrict__ in, u16* __restrict__ th, int K, int N) {
  __shared__ float t[32][33];
  int lx = threadIdx.x;  // 32
  int ly = threadIdx.y;  // 8
  int n0 = blockIdx.x * 32, k0 = blockIdx.y * 32;
#pragma unroll
  for (int i = 0; i < 4; ++i)
    t[ly + 8 * i][lx] = in[(size_t)(k0 + ly + 8 * i) * N + n0 + lx];
  __syncthreads();
#pragma unroll
  for (int i = 0; i < 4; ++i) {
    float v = t[lx][ly + 8 * i];
    th[(size_t)(n0 + ly + 8 * i) * K + k0 + lx] = f2bf(v);
  }
}

// x [16384][512] fp32 -> Xh = bf16(x), Xb = bf16(xb), Xsq = bf16(xb*xb)
__global__ __launch_bounds__(256) void conv_x_kernel(
    const float* __restrict__ x, const float* __restrict__ scale,
    const float* __restrict__ shift, u16* __restrict__ xh,
    u16* __restrict__ xb, u16* __restrict__ xsq) {
  int gid = blockIdx.x * 256 + threadIdx.x;
  int m = gid >> 6;
  int d0 = (gid & 63) * 8;
  f4 v0 = *(const f4*)(x + (size_t)m * 512 + d0);
  f4 v1 = *(const f4*)(x + (size_t)m * 512 + d0 + 4);
  f4 s0 = *(const f4*)(scale + d0);
  f4 s1 = *(const f4*)(scale + d0 + 4);
  f4 h0 = *(const f4*)(shift + d0);
  f4 h1 = *(const f4*)(shift + d0 + 4);
  us8 oh, ob, oq;
#pragma unroll
  for (int e = 0; e < 8; ++e) {
    float xv = (e < 4) ? v0[e] : v1[e - 4];
    float sc = (e < 4) ? s0[e] : s1[e - 4];
    float sh = (e < 4) ? h0[e] : h1[e - 4];
    oh[e] = f2bf(xv);
    float xbf = fmaf(xv, sc, sh);
    ob[e] = f2bf(xbf);
    oq[e] = f2bf(xbf * xbf);
  }
  *(us8*)(xh + (size_t)m * 512 + d0) = oh;
  *(us8*)(xb + (size_t)m * 512 + d0) = ob;
  *(us8*)(xsq + (size_t)m * 512 + d0) = oq;
}

__device__ __forceinline__ void wait_vm8() {
  asm volatile("s_waitcnt vmcnt(8)" ::: "memory");
}
__device__ __forceinline__ void wait_vm0() {
  asm volatile("s_waitcnt vmcnt(0)" ::: "memory");
}
__device__ __forceinline__ void sbar() { __builtin_amdgcn_s_barrier(); }
__device__ __forceinline__ void sgb0() { __builtin_amdgcn_sched_barrier(0); }

// Merged G1+G2, counted-vmcnt 2-tile-ahead pipeline. 1024 blocks, 128x128,
// BK=64, LDS 64KB. (unchanged — measured best)
__global__ __launch_bounds__(256, 2) void gemm_fused12(
    const u16* __restrict__ Xh, const u16* __restrict__ Xb,
    const u16* __restrict__ Xsq, const u16* __restrict__ W1th,
    const u16* __restrict__ Pth, const float* __restrict__ b1,
    const float* __restrict__ cvec, u16* __restrict__ Hout) {
  extern __shared__ char smem[];
  const int tid = threadIdx.x;
  const int l = tid & 63;
  const int w = tid >> 6;
  const int wm = w & 1, wn = w >> 1;
  const int lr = l & 15, lk = l >> 4;
  const int sx = lr & 7;
  const int bid = blockIdx.x;
  const int L = (bid & 7) * 128 + (bid >> 3);
  const int p = L >> 3;
  const int g = ((L >> 2) & 1) ^ 1;
  const int n = L & 3;
  const int m0 = p * 128, n0 = n * 128;
  const int Kg = g ? 1024 : 512;
  const int nt = g ? 16 : 8;
  const u16* Bmat = g ? Pth : W1th;
  const int srow = l >> 3;
  const int sslot = (l & 7) ^ srow;

  f32x4 acc[4][4];
#pragma unroll
  for (int i = 0; i < 4; ++i)
#pragma unroll
    for (int j = 0; j < 4; ++j) acc[i][j] = (f32x4){0.f, 0.f, 0.f, 0.f};

#define F12_STAGE(buf, k0)                                                    \
  {                                                                           \
    const u16* Asrc = g ? (((k0) < 512) ? Xsq : Xb) : Xh;                     \
    const int kb = (k0)&511;                                                  \
    char* dA = smem + (buf)*16384;                                            \
    char* dB = smem + 32768 + (buf)*16384;                                    \
    _Pragma("unroll") for (int pp = 0; pp < 4; ++pp) {                        \
      int c = pp * 4 + w;                                                     \
      int row = c * 8 + srow;                                                 \
      int loff = c * 1024;                                                    \
      size_t goa = (size_t)(m0 + row) * 512 + kb + sslot * 8;                 \
      size_t gob = (size_t)(n0 + row) * Kg + (k0) + sslot * 8;                \
      __builtin_amdgcn_global_load_lds(                                       \
          (const __attribute__((address_space(1))) void*)(Asrc + goa),        \
          (__attribute__((address_space(3))) void*)(dA + loff), 16, 0, 0);    \
      __builtin_amdgcn_global_load_lds(                                       \
          (const __attribute__((address_space(1))) void*)(Bmat + gob),        \
          (__attribute__((address_space(3))) void*)(dB + loff), 16, 0, 0);    \
    }                                                                         \
  }

  F12_STAGE(0, 0);
  F12_STAGE(1, 64);
  for (int t = 0; t < nt; ++t) {
    if (t + 1 < nt) {
      wait_vm8();
    } else {
      wait_vm0();
    }
    sgb0();
    sbar();
    sgb0();
    const char* sA = smem + (t & 1) * 16384;
    const char* sB = smem + 32768 + (t & 1) * 16384;
#pragma unroll
    for (int ks = 0; ks < 2; ++ks) {
      bf16x8 av[4], bv[4];
#pragma unroll
      for (int i = 0; i < 4; ++i)
        av[i] = *(const bf16x8*)(sA + (wm * 64 + i * 16 + lr) * 128 +
                                 (((ks * 4 + lk) ^ sx) * 16));
#pragma unroll
      for (int j = 0; j < 4; ++j)
        bv[j] = *(const bf16x8*)(sB + (wn * 64 + j * 16 + lr) * 128 +
                                 (((ks * 4 + lk) ^ sx) * 16));
#pragma unroll
      for (int i = 0; i < 4; ++i)
#pragma unroll
        for (int j = 0; j < 4; ++j)
          acc[i][j] = __builtin_amdgcn_mfma_f32_16x16x32_bf16(av[i], bv[j],
                                                              acc[i][j], 0, 0, 0);
    }
    sgb0();
    sbar();
    sgb0();
    if (t + 2 < nt) F12_STAGE(t & 1, (t + 2) * 64);
  }
#undef F12_STAGE

  const int mwb = m0 + wm * 64;
  const int nwb = n0 + wn * 64;
  const float* bias = g ? cvec : b1;
#pragma unroll
  for (int j = 0; j < 4; ++j) {
    int nn = nwb + j * 16 + lr;
    float bv = bias[nn];
#pragma unroll
    for (int i = 0; i < 4; ++i) {
#pragma unroll
      for (int r = 0; r < 4; ++r) {
        int m = mwb + i * 16 + lk * 4 + r;
        float v = acc[i][j][r] + bv;
        v = g ? fmaxf(1.f - v, 0.f) : fmaxf(v, 0.f);
        Hout[(size_t)m * 1024 + g * 512 + nn] = f2bf(v);
      }
    }
  }
}

// G3: pre = w0*x + w1*relu(Hh @ Wth^T + b_out), stored BF16 (halves the
// pre round-trip traffic; adds <= 1 bf16 ulp to pre, budgeted vs 2e-2).
// K=1024, counted-vmcnt 2-ahead pipeline, LDS 64KB. 512 blocks, XCD swizzle.
__global__ __launch_bounds__(256, 2) void gemm3(
    const u16* __restrict__ Ah, const u16* __restrict__ Bh,
    const float* __restrict__ bias, const float* __restrict__ xorig,
    const float* __restrict__ wadd, u16* __restrict__ preb) {
  extern __shared__ char smem[];
  const int tid = threadIdx.x;
  const int l = tid & 63;
  const int w = tid >> 6;
  const int wm = w & 1, wn = w >> 1;
  const int lr = l & 15, lk = l >> 4;
  const int sx = lr & 7;
  const int bid = blockIdx.x;
  const int lin = (bid & 7) * 64 + (bid >> 3);
  const int m0 = (lin >> 2) * 128, n0 = (lin & 3) * 128;
  const int srow = l >> 3;
  const int sslot = (l & 7) ^ srow;

  f32x4 acc[4][4];
#pragma unroll
  for (int i = 0; i < 4; ++i)
#pragma unroll
    for (int j = 0; j < 4; ++j) acc[i][j] = (f32x4){0.f, 0.f, 0.f, 0.f};

#define G3_STAGE(buf, k0)                                                     \
  {                                                                           \
    char* dA = smem + (buf)*16384;                                            \
    char* dB = smem + 32768 + (buf)*16384;                                    \
    _Pragma("unroll") for (int pp = 0; pp < 4; ++pp) {                        \
      int c = pp * 4 + w;                                                     \
      int row = c * 8 + srow;                                                 \
      int loff = c * 1024;                                                    \
      size_t gob = (size_t)(n0 + row) * 1024 + (k0) + sslot * 8;              \
      size_t goa = (size_t)(m0 + row) * 1024 + (k0) + sslot * 8;              \
      __builtin_amdgcn_global_load_lds(                                       \
          (const __attribute__((address_space(1))) void*)(Bh + gob),          \
          (__attribute__((address_space(3))) void*)(dB + loff), 16, 0, 0);    \
      __builtin_amdgcn_global_load_lds(                                       \
          (const __attribute__((address_space(1))) void*)(Ah + goa),          \
          (__attribute__((address_space(3))) void*)(dA + loff), 16, 0, 0);    \
    }                                                                         \
  }

  G3_STAGE(0, 0);
  G3_STAGE(1, 64);
  for (int t = 0; t < 16; ++t) {
    if (t + 1 < 16) {
      wait_vm8();
    } else {
      wait_vm0();
    }
    sgb0();
    sbar();
    sgb0();
    const char* sA = smem + (t & 1) * 16384;
    const char* sB = smem + 32768 + (t & 1) * 16384;
#pragma unroll
    for (int ks = 0; ks < 2; ++ks) {
      bf16x8 av[4], bv[4];
#pragma unroll
      for (int i = 0; i < 4; ++i)
        av[i] = *(const bf16x8*)(sA + (wm * 64 + i * 16 + lr) * 128 +
                                 (((ks * 4 + lk) ^ sx) * 16));
#pragma unroll
      for (int j = 0; j < 4; ++j)
        bv[j] = *(const bf16x8*)(sB + (wn * 64 + j * 16 + lr) * 128 +
                                 (((ks * 4 + lk) ^ sx) * 16));
#pragma unroll
      for (int i = 0; i < 4; ++i)
#pragma unroll
        for (int j = 0; j < 4; ++j)
          acc[i][j] = __builtin_amdgcn_mfma_f32_16x16x32_bf16(av[i], bv[j],
                                                              acc[i][j], 0, 0, 0);
    }
    sgb0();
    sbar();
    sgb0();
    if (t + 2 < 16) G3_STAGE(t & 1, (t + 2) * 64);
  }
#undef G3_STAGE

  const int mwb = m0 + wm * 64;
  const int nwb = n0 + wn * 64;
  float w0 = wadd[0], w1 = wadd[1];
#pragma unroll
  for (int j = 0; j < 4; ++j) {
    int n = nwb + j * 16 + lr;
    float bv = bias[n];
#pragma unroll
    for (int i = 0; i < 4; ++i) {
#pragma unroll
      for (int r = 0; r < 4; ++r) {
        int m = mwb + i * 16 + lk * 4 + r;
        float v = fmaxf(acc[i][j][r] + bv, 0.f);
        preb[(size_t)m * 512 + n] =
            f2bf(fmaf(w1, v, w0 * xorig[(size_t)m * 512 + n]));
      }
    }
  }
}

// One wave per row of 512: read bf16 pre, compute sparsemax in f32, write
// f32 mask. XCD-aligned work swizzle (pre row panels -> producing XCD L2).
__global__ __launch_bounds__(256) void sparsemax_kernel(
    const u16* __restrict__ pre, float* __restrict__ out) {
  int wrk = (blockIdx.x & 7) * 512 + (blockIdx.x >> 3);
  int row = wrk * 4 + (threadIdx.x >> 6);
  int lane = threadIdx.x & 63;
  const u16* rp = pre + (size_t)row * 512;
  us8 zv = *(const us8*)(rp + lane * 8);
  float z[8];
#pragma unroll
  for (int e = 0; e < 8; ++e) z[e] = bf2f(zv[e]);
  float m = z[0];
#pragma unroll
  for (int i = 1; i < 8; ++i) m = fmaxf(m, z[i]);
#pragma unroll
  for (int off = 32; off; off >>= 1) m = fmaxf(m, __shfl_xor(m, off));
  float tau = m - 1.0f;
  for (int it = 0; it < 32; ++it) {
    float s = 0.f, k = 0.f;
#pragma unroll
    for (int i = 0; i < 8; ++i) {
      if (z[i] > tau) {
        s += z[i] - tau;
        k += 1.f;
      }
    }
#pragma unroll
    for (int off = 32; off; off >>= 1) {
      s += __shfl_xor(s, off);
      k += __shfl_xor(k, off);
    }
    if (k < 0.5f) break;
    float tn = tau + (s - 1.f) / k;
    if (tn == tau) break;
    tau = tn;
  }
  float s = 0.f, k = 0.f;
#pragma unroll
  for (int i = 0; i < 8; ++i)
    if (z[i] > tau) {
      s += z[i];
      k += 1.f;
    }
#pragma unroll
  for (int off = 32; off; off >>= 1) {
    s += __shfl_xor(s, off);
    k += __shfl_xor(k, off);
  }
  float tauf = (k >= 0.5f) ? (s - 1.f) / k : (m - 1.f);
  float* op = out + (size_t)row * 512 + lane * 8;
  f4 o0, o1;
#pragma unroll
  for (int e = 0; e < 4; ++e) {
    o0[e] = fmaxf(z[e] - tauf, 0.f);
    o1[e] = fmaxf(z[4 + e] - tauf, 0.f);
  }
  *(f4*)(op) = o0;
  *(f4*)(op + 4) = o1;
}

extern "C" void kernel_launch(void* const* d_in, const int* in_sizes, int n_in,
                              void* d_out, int out_size, void* d_ws,
                              size_t ws_size, hipStream_t stream) {
  const float* x = (const float*)d_in[0];
  const float* W1 = (const float*)d_in[1];
  const float* b1 = (const float*)d_in[2];
  const float* centers = (const float*)d_in[3];
  const float* coefs = (const float*)d_in[4];
  const float* gamma = (const float*)d_in[5];
  const float* beta = (const float*)d_in[6];
  const float* mean = (const float*)d_in[7];
  const float* var = (const float*)d_in[8];
  const float* W_out = (const float*)d_in[9];
  const float* b_out = (const float*)d_in[10];
  const float* wadd = (const float*)d_in[11];
  float* out = (float*)d_out;

  // Base layout: 69,212,160 B == round-1-proven ws_size floor.
  char* ws = (char*)d_ws;
  u16* Hh = (u16*)(ws);                      // [16384][1024] bf16 = 32 MB
  u16* Xh = (u16*)(ws + 33554432);           // [16384][512]  bf16 = 16 MB
  u16* Xb = (u16*)(ws + 50331648);           // [16384][512]  bf16 = 16 MB
  char* pool = ws + 67108864;                // 2 MB
  u16* W1th = (u16*)(pool);
  u16* Pth = (u16*)(pool + 1048576);
  float* cvec = (float*)(ws + 69206016);     // 2 KB
  float* scale = (float*)(ws + 69208064);    // 2 KB
  float* shift = (float*)(ws + 69210112);    // 2 KB
  // Xsq lives in d_out (32 MB fp32): dead scratch until sparsemax overwrites.
  u16* Xsq = (u16*)d_out;
  // bf16 pre reuses the Xb slot (dead after fused12, stream-ordered).
  u16* preb = Xb;
  const bool bigws = (ws_size >= (size_t)70260736);
  u16* Wth = bigws ? (u16*)(ws + 69212160) : (u16*)(pool);

  prep_bn_kernel<<<2, 256, 0, stream>>>(gamma, beta, mean, var, scale, shift);
  prep_params_kernel<<<512, 64, 0, stream>>>(coefs, centers, Pth, cvec);
  transpose_split_kernel<<<dim3(16, 16), dim3(32, 8), 0, stream>>>(W1, W1th,
                                                                   512, 512);
  if (bigws) {
    transpose_split_kernel<<<dim3(16, 32), dim3(32, 8), 0, stream>>>(
        W_out, Wth, 1024, 512);
  }
  conv_x_kernel<<<4096, 256, 0, stream>>>(x, scale, shift, Xh, Xb, Xsq);

  gemm_fused12<<<1024, 256, 65536, stream>>>(Xh, Xb, Xsq, W1th, Pth, b1, cvec,
                                             Hh);

  if (!bigws) {
    transpose_split_kernel<<<dim3(16, 32), dim3(32, 8), 0, stream>>>(
        W_out, Wth, 1024, 512);
  }
  gemm3<<<512, 256, 65536, stream>>>(Hh, Wth, b_out, x, wadd, preb);
  sparsemax_kernel<<<4096, 256, 0, stream>>>(preb, out);
}